// Round 1
// baseline (507.395 us; speedup 1.0000x reference)
//
#include <hip/hip_runtime.h>

// ---------------------------------------------------------------------------
// DifferentiableTreeDense: out[b, l*128+o] =
//    leaf_prob[b,l] * (dot(x[b,:], leaf_w[l,:,o]) + bias[l,o])
// leaf_prob[b,l] = prod_d sigmoid(logit[b,node_d,dir_d] - logit[b,node_d,!dir_d])
// logit[b,n,d]   = dot(x[b,:], routing_w[n,:,d])
//
// Strategy: bf16 MFMA GEMM (m97 structure) for both einsums; fp32 epilogue.
// ---------------------------------------------------------------------------

typedef __attribute__((ext_vector_type(8))) short short8;
typedef __attribute__((ext_vector_type(4))) float f32x4;

#define BATCH 8192
#define FEAT  1024
#define NLEAF 64
#define LEAFD 128
#define OUTD  8192

__device__ __forceinline__ unsigned short f2bf(float f) {
    union { float f; unsigned int u; } c; c.f = f;
    unsigned int u = c.u;
    return (unsigned short)((u + 0x7FFFu + ((u >> 16) & 1u)) >> 16);  // RNE
}

__device__ __forceinline__ void gload16(const void* g, void* l) {
    // async global->LDS, 16B per lane. LDS side must be wave-uniform base + lane*16.
    __builtin_amdgcn_global_load_lds(
        (const __attribute__((address_space(1))) unsigned int*)g,
        (__attribute__((address_space(3))) unsigned int*)l, 16, 0, 0);
}

// --------------------------- conversion kernels ----------------------------

// x fp32 [8192][1024] -> bf16 same layout
__global__ __launch_bounds__(256) void cvt_x(const float* __restrict__ x,
                                             unsigned short* __restrict__ xb) {
    const int i = (blockIdx.x * 256 + threadIdx.x) * 4;
    const float4 v = *(const float4*)(x + i);
    ushort4 o;
    o.x = f2bf(v.x); o.y = f2bf(v.y); o.z = f2bf(v.z); o.w = f2bf(v.w);
    *(ushort4*)(xb + i) = o;
}

// leaf_weights fp32 [64][1024][128] -> bf16 transposed [64][128][1024]
__global__ __launch_bounds__(256) void cvt_lw(const float* __restrict__ lw,
                                              unsigned short* __restrict__ wt) {
    __shared__ float tile[32][33];                 // +1 pad: conflict-free transpose
    const int l  = blockIdx.x;                     // 0..63
    const int k0 = blockIdx.y * 32;                // 0..1023
    const int o0 = blockIdx.z * 32;                // 0..127
    const int tr = threadIdx.x >> 5;               // 0..7
    const int tc = threadIdx.x & 31;               // 0..31
    const float* src = lw + (size_t)l * (FEAT * LEAFD);
#pragma unroll
    for (int p = 0; p < 4; ++p) {
        const int r = p * 8 + tr;
        tile[r][tc] = src[(size_t)(k0 + r) * LEAFD + o0 + tc];
    }
    __syncthreads();
    unsigned short* dst = wt + (size_t)l * (LEAFD * FEAT);
#pragma unroll
    for (int p = 0; p < 4; ++p) {
        const int oo = p * 8 + tr;
        dst[(size_t)(o0 + oo) * FEAT + k0 + tc] = f2bf(tile[tc][oo]);
    }
}

// routing_weights fp32 [63][1024][2] -> bf16 [128][1024], row = n*2+d, rows 126/127 = 0
__global__ __launch_bounds__(256) void cvt_rw(const float* __restrict__ rw,
                                              unsigned short* __restrict__ rt) {
    const int gid = blockIdx.x * 256 + threadIdx.x;   // 128*1024 total
    const int row = gid >> 10;
    const int f   = gid & 1023;
    const float v = (row < 126) ? rw[(size_t)(row >> 1) * 2048 + f * 2 + (row & 1)] : 0.0f;
    rt[gid] = f2bf(v);
}

// ----------------------------- routing GEMM --------------------------------
// logits[8192][128] = x_bf16 @ Rt^T ; grid = 64 blocks (one per 128 batch rows)
__global__ __launch_bounds__(256) void routing_gemm(
        const unsigned short* __restrict__ xb,
        const unsigned short* __restrict__ rt,
        float* __restrict__ logits) {
    __shared__ __align__(16) unsigned short As[128 * 32];
    __shared__ __align__(16) unsigned short Bs[128 * 32];
    const int t    = threadIdx.x;
    const int row0 = blockIdx.x * 128;
    const int wv = t >> 6, ln = t & 63;
    const int wm = wv >> 1, wn = wv & 1;
    const int quad = ln >> 4, r16 = ln & 15;

    f32x4 acc[4][4];
#pragma unroll
    for (int i = 0; i < 4; ++i)
#pragma unroll
        for (int j = 0; j < 4; ++j) acc[i][j] = (f32x4)0.0f;

    const unsigned short* ag = xb + (size_t)row0 * FEAT;
    const int srow = t >> 2;
    const int scol = (t & 3) * 8;

    for (int k0 = 0; k0 < FEAT; k0 += 32) {
#pragma unroll
        for (int i = 0; i < 2; ++i) {
            gload16(ag + (size_t)(i * 64 + srow) * FEAT + k0 + scol,
                    (char*)As + i * 4096 + t * 16);
            gload16(rt + (size_t)(i * 64 + srow) * FEAT + k0 + scol,
                    (char*)Bs + i * 4096 + t * 16);
        }
        __syncthreads();
        short8 a[4], b[4];
#pragma unroll
        for (int mi = 0; mi < 4; ++mi)
            a[mi] = *(const short8*)&As[(wm * 64 + mi * 16 + r16) * 32 + quad * 8];
#pragma unroll
        for (int ni = 0; ni < 4; ++ni)
            b[ni] = *(const short8*)&Bs[(wn * 64 + ni * 16 + r16) * 32 + quad * 8];
#pragma unroll
        for (int mi = 0; mi < 4; ++mi)
#pragma unroll
            for (int ni = 0; ni < 4; ++ni)
                acc[mi][ni] = __builtin_amdgcn_mfma_f32_16x16x32_bf16(
                    a[mi], b[ni], acc[mi][ni], 0, 0, 0);
        __syncthreads();
    }
#pragma unroll
    for (int mi = 0; mi < 4; ++mi) {
        const int r = wm * 64 + mi * 16 + quad * 4;
#pragma unroll
        for (int ni = 0; ni < 4; ++ni) {
            const int c = wn * 64 + ni * 16 + r16;
#pragma unroll
            for (int reg = 0; reg < 4; ++reg)
                logits[(size_t)(row0 + r + reg) * 128 + c] = acc[mi][ni][reg];
        }
    }
}

// ------------------------- leaf probabilities ------------------------------
// lp[b][leaf] = prod_d sigmoid(z_dir - z_other)
__global__ __launch_bounds__(256) void leafprob(
        const float* __restrict__ logits,     // [8192][128]
        const int* __restrict__ pnodes,       // [64][6]
        const int* __restrict__ pdirs,        // [64][6]
        float* __restrict__ lp) {             // [8192][64]
    const int gid  = blockIdx.x * 256 + threadIdx.x;  // 8192*64
    const int b    = gid >> 6;
    const int leaf = gid & 63;
    float prod = 1.0f;
#pragma unroll
    for (int d = 0; d < 6; ++d) {
        const int n   = pnodes[leaf * 6 + d];
        const int dir = pdirs[leaf * 6 + d];
        if (n >= 0) {
            const float z0 = logits[(size_t)b * 128 + n * 2];
            const float z1 = logits[(size_t)b * 128 + n * 2 + 1];
            const float zd = dir ? z1 : z0;
            const float zo = dir ? z0 : z1;
            prod *= 1.0f / (1.0f + __expf(zo - zd));
        }
    }
    lp[gid] = prod;
}

// ------------------------------ main GEMM ----------------------------------
// out[b][l*128+c] = lp[b][l] * (sum_k x[b][k]*Wt[l][c][k] + bias[l][c])
// grid = (64 mtiles, 64 leaves); 128x128 tile, BK=32, 4 waves of 4x4 MFMA tiles
__global__ __launch_bounds__(256) void leaf_gemm(
        const unsigned short* __restrict__ xb,   // [8192][1024] bf16
        const unsigned short* __restrict__ wt,   // [64][128][1024] bf16
        const float* __restrict__ lp,            // [8192][64]
        const float* __restrict__ bias,          // [64][128]
        float* __restrict__ out) {               // [8192][8192]
    __shared__ __align__(16) unsigned short As[128 * 32];
    __shared__ __align__(16) unsigned short Bs[128 * 32];
    __shared__ float lps[128];
    __shared__ float bs[128];

    const int t    = threadIdx.x;
    const int row0 = blockIdx.x * 128;       // batch tile
    const int l    = blockIdx.y;             // leaf = column tile

    if (t < 128) {
        lps[t] = lp[(size_t)(row0 + t) * NLEAF + l];
        bs[t]  = bias[l * LEAFD + t];
    }

    const int wv = t >> 6, ln = t & 63;
    const int wm = wv >> 1, wn = wv & 1;
    const int quad = ln >> 4, r16 = ln & 15;

    f32x4 acc[4][4];
#pragma unroll
    for (int i = 0; i < 4; ++i)
#pragma unroll
        for (int j = 0; j < 4; ++j) acc[i][j] = (f32x4)0.0f;

    const unsigned short* ag = xb + (size_t)row0 * FEAT;
    const unsigned short* bg = wt + (size_t)l * (LEAFD * FEAT);
    const int srow = t >> 2;
    const int scol = (t & 3) * 8;

    for (int k0 = 0; k0 < FEAT; k0 += 32) {
#pragma unroll
        for (int i = 0; i < 2; ++i) {
            gload16(ag + (size_t)(i * 64 + srow) * FEAT + k0 + scol,
                    (char*)As + i * 4096 + t * 16);
            gload16(bg + (size_t)(i * 64 + srow) * FEAT + k0 + scol,
                    (char*)Bs + i * 4096 + t * 16);
        }
        __syncthreads();
        short8 a[4], b[4];
#pragma unroll
        for (int mi = 0; mi < 4; ++mi)
            a[mi] = *(const short8*)&As[(wm * 64 + mi * 16 + r16) * 32 + quad * 8];
#pragma unroll
        for (int ni = 0; ni < 4; ++ni)
            b[ni] = *(const short8*)&Bs[(wn * 64 + ni * 16 + r16) * 32 + quad * 8];
#pragma unroll
        for (int mi = 0; mi < 4; ++mi)
#pragma unroll
            for (int ni = 0; ni < 4; ++ni)
                acc[mi][ni] = __builtin_amdgcn_mfma_f32_16x16x32_bf16(
                    a[mi], b[ni], acc[mi][ni], 0, 0, 0);
        __syncthreads();
    }

    // epilogue: (acc + bias) * leaf_prob
#pragma unroll
    for (int mi = 0; mi < 4; ++mi) {
        const int r = wm * 64 + mi * 16 + quad * 4;
#pragma unroll
        for (int ni = 0; ni < 4; ++ni) {
            const int c  = wn * 64 + ni * 16 + r16;
            const float bv = bs[c];
#pragma unroll
            for (int reg = 0; reg < 4; ++reg) {
                const float v = (acc[mi][ni][reg] + bv) * lps[r + reg];
                out[(size_t)(row0 + r + reg) * OUTD + l * LEAFD + c] = v;
            }
        }
    }
}

// ------------------------------- launcher ----------------------------------

extern "C" void kernel_launch(void* const* d_in, const int* in_sizes, int n_in,
                              void* d_out, int out_size, void* d_ws, size_t ws_size,
                              hipStream_t stream) {
    const float* x    = (const float*)d_in[0];   // [8192][1024]
    const float* rw   = (const float*)d_in[1];   // [63][1024][2]
    const float* lw   = (const float*)d_in[2];   // [64][1024][128]
    const float* bias = (const float*)d_in[3];   // [64][128]
    const int*   pn   = (const int*)d_in[4];     // [64][6]
    const int*   pd   = (const int*)d_in[5];     // [64][6]
    float* out = (float*)d_out;

    char* ws = (char*)d_ws;
    unsigned short* xb     = (unsigned short*)(ws);               // 16 MB
    unsigned short* wt     = (unsigned short*)(ws + 16777216);    // 16 MB
    unsigned short* rt     = (unsigned short*)(ws + 33554432);    // 256 KB
    float*          logits = (float*)(ws + 33816576);             // 4 MB
    float*          lpv    = (float*)(ws + 38010880);             // 2 MB

    cvt_x<<<8192, 256, 0, stream>>>(x, xb);
    cvt_lw<<<dim3(64, 32, 4), 256, 0, stream>>>(lw, wt);
    cvt_rw<<<512, 256, 0, stream>>>(rw, rt);
    routing_gemm<<<64, 256, 0, stream>>>(xb, rt, logits);
    leafprob<<<2048, 256, 0, stream>>>(logits, pn, pd, lpv);
    leaf_gemm<<<dim3(64, 64), 256, 0, stream>>>(xb, wt, lpv, bias, out);
}